// Round 2
// baseline (679.861 us; speedup 1.0000x reference)
//
#include <hip/hip_runtime.h>

#define CODEBOOK 131072
#define DIM 1024
#define ROWS_PER_WAVE 8
#define WAVES_PER_BLOCK 4
#define ROWS_PER_BLOCK (ROWS_PER_WAVE * WAVES_PER_BLOCK)   // 32
#define NB (CODEBOOK / ROWS_PER_BLOCK)                     // 4096 blocks

__device__ __forceinline__ unsigned long long shfl_down_u64(unsigned long long v, int off) {
    unsigned lo = (unsigned)(v & 0xFFFFFFFFu);
    unsigned hi = (unsigned)(v >> 32);
    lo = __shfl_down(lo, off, 64);
    hi = __shfl_down(hi, off, 64);
    return ((unsigned long long)hi << 32) | (unsigned long long)lo;
}

// Order-preserving float -> u32 key (monotone increasing).
__device__ __forceinline__ unsigned float_key(float f) {
    unsigned u = __float_as_uint(f);
    return (u & 0x80000000u) ? ~u : (u | 0x80000000u);
}

// Kernel 1: dots for 8 rows per wave.
// K is processed in 4 chunks of 256 floats; per chunk each lane issues 8
// independent dwordx4 loads (one per row, 1 KB/wave-instr each) then FMAs
// into 8 scalar accumulators. unroll 1 on the chunk loop caps VGPR pressure
// (~80 regs) while keeping MLP=8 per wave. All cross-lane reduction is in
// the tail: 8 accs x 6 shfl steps once per wave.
__global__ __launch_bounds__(256) void vq_dot_kernel(const float* __restrict__ z,
                                                     const float* __restrict__ W,
                                                     unsigned long long* __restrict__ partials) {
    const int lane = threadIdx.x & 63;
    const int wave = threadIdx.x >> 6;

    const float4* z4 = (const float4*)z;
    float4 zr[4];
#pragma unroll
    for (int j = 0; j < 4; ++j) zr[j] = z4[j * 64 + lane];

    const int row0 = blockIdx.x * ROWS_PER_BLOCK + wave * ROWS_PER_WAVE;
    const float4* Wbase = (const float4*)(W + (size_t)row0 * DIM);  // 256 float4 per row

    float acc[ROWS_PER_WAVE];
#pragma unroll
    for (int r = 0; r < ROWS_PER_WAVE; ++r) acc[r] = 0.f;

#pragma unroll 1
    for (int j = 0; j < 4; ++j) {
        float4 w[ROWS_PER_WAVE];
#pragma unroll
        for (int r = 0; r < ROWS_PER_WAVE; ++r)
            w[r] = Wbase[(size_t)r * 256 + j * 64 + lane];
        const float4 zj = zr[j];
#pragma unroll
        for (int r = 0; r < ROWS_PER_WAVE; ++r) {
            acc[r] = fmaf(w[r].x, zj.x, acc[r]);
            acc[r] = fmaf(w[r].y, zj.y, acc[r]);
            acc[r] = fmaf(w[r].z, zj.z, acc[r]);
            acc[r] = fmaf(w[r].w, zj.w, acc[r]);
        }
    }

    // Tail reduction: butterfly each of the 8 row-sums across the wave.
#pragma unroll
    for (int off = 32; off > 0; off >>= 1) {
#pragma unroll
        for (int r = 0; r < ROWS_PER_WAVE; ++r)
            acc[r] += __shfl_down(acc[r], off, 64);
    }

    unsigned long long best = 0ULL;  // below any real key (dots in [-1,1])
    if (lane == 0) {
#pragma unroll
        for (int r = 0; r < ROWS_PER_WAVE; ++r) {
            // key in high 32 bits; ~row in low 32 so ties prefer LOWER row
            unsigned long long p =
                ((unsigned long long)float_key(acc[r]) << 32) |
                (unsigned long long)(~(unsigned)(row0 + r));
            if (p > best) best = p;
        }
    }

    __shared__ unsigned long long sbest[WAVES_PER_BLOCK];
    if (lane == 0) sbest[wave] = best;
    __syncthreads();
    if (threadIdx.x == 0) {
        unsigned long long b = sbest[0];
#pragma unroll
        for (int i = 1; i < WAVES_PER_BLOCK; ++i)
            if (sbest[i] > b) b = sbest[i];
        partials[blockIdx.x] = b;
    }
}

// Kernel 2: reduce 4096 partials -> index; emit quantized_st, index, loss.
__global__ __launch_bounds__(256) void vq_finalize(const float* __restrict__ z,
                                                   const float* __restrict__ W,
                                                   const unsigned long long* __restrict__ partials,
                                                   float* __restrict__ out) {
    __shared__ unsigned long long swin[WAVES_PER_BLOCK];
    __shared__ float ssum[WAVES_PER_BLOCK];
    const int tid = threadIdx.x;
    const int lane = tid & 63;
    const int wave = tid >> 6;

    unsigned long long best = 0ULL;
#pragma unroll 4
    for (int i = tid; i < NB; i += 256) {
        unsigned long long p = partials[i];
        if (p > best) best = p;
    }
#pragma unroll
    for (int off = 32; off > 0; off >>= 1) {
        unsigned long long o = shfl_down_u64(best, off);
        if (o > best) best = o;
    }
    if (lane == 0) swin[wave] = best;
    __syncthreads();
    if (tid == 0) {
        unsigned long long b = swin[0];
#pragma unroll
        for (int i = 1; i < WAVES_PER_BLOCK; ++i)
            if (swin[i] > b) b = swin[i];
        swin[0] = b;
    }
    __syncthreads();

    const unsigned idx = ~(unsigned)(swin[0] & 0xFFFFFFFFu);
    const float4* Wrow = (const float4*)(W + (size_t)idx * DIM);
    const float4* z4 = (const float4*)z;

    float4 q = Wrow[tid];       // 256 threads x float4 = 1024 elements
    float4 zv = z4[tid];

    // straight-through estimator arithmetic, matching the reference exactly:
    float4 st;
    st.x = zv.x + (q.x - zv.x);
    st.y = zv.y + (q.y - zv.y);
    st.z = zv.z + (q.z - zv.z);
    st.w = zv.w + (q.w - zv.w);
    ((float4*)out)[tid] = st;

    float dx = zv.x - q.x, dy = zv.y - q.y, dz = zv.z - q.z, dw = zv.w - q.w;
    float s = dx * dx + dy * dy + dz * dz + dw * dw;
#pragma unroll
    for (int off = 32; off > 0; off >>= 1)
        s += __shfl_down(s, off, 64);
    if (lane == 0) ssum[wave] = s;
    __syncthreads();
    if (tid == 0) {
        float tot = ssum[0] + ssum[1] + ssum[2] + ssum[3];
        out[DIM] = (float)idx;                          // index (exact in fp32)
        out[DIM + 1] = 0.25f * (tot / (float)DIM);      // commitment loss
    }
}

extern "C" void kernel_launch(void* const* d_in, const int* in_sizes, int n_in,
                              void* d_out, int out_size, void* d_ws, size_t ws_size,
                              hipStream_t stream) {
    const float* z = (const float*)d_in[0];
    const float* W = (const float*)d_in[1];
    float* out = (float*)d_out;
    unsigned long long* partials = (unsigned long long*)d_ws;  // 4096 * 8 B = 32 KB

    vq_dot_kernel<<<NB, 256, 0, stream>>>(z, W, partials);
    vq_finalize<<<1, 256, 0, stream>>>(z, W, partials, out);
}